// Round 5
// baseline (665.673 us; speedup 1.0000x reference)
//
#include <hip/hip_runtime.h>

// Problem constants (match reference)
#define K_     1056
#define N_     2112
#define M_     1056   // N - K
#define DV_    5
#define ROW_   6      // DV + 1 edges per check; edge 6m+5 is the parity VN K+m
#define NSYM_  528
#define NITER_ 20
#define BATCH_ 1024

// -------------------------------------------------------------------------
// Single fused kernel, one block per codeword.
//
// Structure exploited: H = [A | I].
//  * Parity VN (degree 1): its VN->CN message is ALWAYS its channel LLR, so
//    its tanh term t5 is a per-check constant; the CN->parity message (j=5)
//    affects nothing we output and is never computed.
//  * BP state = info-VN marginals only. Two K-float LDS buffers ping-pong:
//    read tot from bufA, atomicAdd new c2v into bufB (pre-reset to channel
//    LLR); old c2v lives in registers (c2vr[5][5]) for extrinsic subtract.
//  * No CSR, no build kernels: edge_vn is read directly (5 info edges/check).
//
// CN math (product form, HW v_exp/v_log, signs carried in t):
//   t_i = copysign((1-e^{-av})/(1+e^{-av}), v2c)   [= tanh(v2c/2), clipped]
//   P   = t5 * prod t_i
//   q_j = clamp(P / t_j, +-0.99999988)             [ref caps at exp(-1e-7)]
//   r_j = log((1+q_j)/(1-q_j))                     [= 2 atanh(q_j)]
// -------------------------------------------------------------------------
__global__ __launch_bounds__(256) void link_kernel(
    const int*   __restrict__ bits,      // [B,K]
    const int*   __restrict__ a_idx,     // [M,DV]
    const float* __restrict__ points_re, // [16]
    const float* __restrict__ points_im, // [16]
    const float* __restrict__ noise_re,  // [B,NSYM]
    const float* __restrict__ noise_im,  // [B,NSYM]
    const float* __restrict__ ebno_db,   // [1]
    const int*   __restrict__ edge_vn,   // [E]
    float*       __restrict__ out)       // [2,B,K]
{
#pragma clang fp contract(off)
    const int b   = blockIdx.x;
    const int tid = threadIdx.x;

    __shared__ float s_mem[N_];          // [0..K): bufA, [K..2K): bufB
    __shared__ float s_pre[16];
    __shared__ float s_pim[16];
    float* bufA = s_mem;
    float* bufB = s_mem + K_;

    if (tid < 16) {
        s_pre[tid] = points_re[tid];
        s_pim[tid] = points_im[tid];
    }

    const float eb    = ebno_db[0];
    const float no    = 1.0f / ((powf(10.0f, eb / 10.0f) * 0.5f) * 4.0f);
    const float sigma = sqrtf(no / 2.0f);

    // ---- stage info bits (0/1 floats); output0 = bits.astype(f32) ----
    for (int i = tid; i < K_; i += 256) {
        int v = bits[b * K_ + i];
        s_mem[i] = (float)v;
        out[b * K_ + i] = (float)v;
    }
    __syncthreads();

    // ---- parity: XOR of DV gathered info bits ----
    for (int m = tid; m < M_; m += 256) {
        float acc = 0.0f;
        #pragma unroll
        for (int d = 0; d < DV_; ++d) acc += s_mem[a_idx[m * DV_ + d]];
        s_mem[K_ + m] = (float)(((int)acc) & 1);
    }
    __syncthreads();

    // ---- QAM map + AWGN + exact APP demap (in-place, own 4 slots) ----
    for (int s = tid; s < NSYM_; s += 256) {
        int c0 = (int)s_mem[4 * s + 0];
        int c1 = (int)s_mem[4 * s + 1];
        int c2 = (int)s_mem[4 * s + 2];
        int c3 = (int)s_mem[4 * s + 3];
        int sym = c0 * 8 + c1 * 4 + c2 * 2 + c3;
        float yre = s_pre[sym] + sigma * noise_re[b * NSYM_ + s];
        float yim = s_pim[sym] + sigma * noise_im[b * NSYM_ + s];
        float lg[16];
        #pragma unroll
        for (int p = 0; p < 16; ++p) {
            float dre  = yre - s_pre[p];
            float dim_ = yim - s_pim[p];
            float d2   = dre * dre + dim_ * dim_;
            lg[p] = -d2 / no;
        }
        float llr4[4];
        #pragma unroll
        for (int j = 0; j < 4; ++j) {
            float m0 = -1e30f, m1 = -1e30f;
            #pragma unroll
            for (int p = 0; p < 16; ++p) {
                if (((p >> (3 - j)) & 1) == 0) m0 = fmaxf(m0, lg[p]);
                else                           m1 = fmaxf(m1, lg[p]);
            }
            float sum0 = 0.0f, sum1 = 0.0f;
            #pragma unroll
            for (int p = 0; p < 16; ++p) {
                if (((p >> (3 - j)) & 1) == 0) sum0 += __expf(lg[p] - m0);
                else                           sum1 += __expf(lg[p] - m1);
            }
            llr4[j] = (m0 + __logf(sum0)) - (m1 + __logf(sum1));
        }
        s_mem[4 * s + 0] = llr4[0];
        s_mem[4 * s + 1] = llr4[1];
        s_mem[4 * s + 2] = llr4[2];
        s_mem[4 * s + 3] = llr4[3];
    }
    __syncthreads();

    // ---- per-check constants: info-edge VN ids + parity tanh t5 ----
    // Thread owns checks m = tid + 256*kk and info VNs v = tid + 256*k
    // (same index pattern -> slot reads/writes below stay intra-thread).
    int   vn[5][5];
    float c2vr[5][5];
    float t5[5];
    #pragma unroll
    for (int kk = 0; kk < 5; ++kk) {
        int m = tid + 256 * kk;
        if (m < M_) {
            #pragma unroll
            for (int j = 0; j < 5; ++j) {
                vn[kk][j]   = edge_vn[m * ROW_ + j];
                c2vr[kk][j] = 0.0f;
            }
            float lrP = bufB[m];                    // parity channel LLR
            float av  = fminf(fmaxf(fabsf(lrP), 1e-6f), 20.0f);
            float e   = __expf(-av);
            float tm  = __fdividef(1.0f - e, 1.0f + e);
            t5[kk] = copysignf(tm, lrP);
        }
    }
    // channel LLRs of owned info VNs; init both accumulators to lr
    float lr[5];
    #pragma unroll
    for (int k = 0; k < 5; ++k) {
        int v = tid + 256 * k;
        if (v < K_) {
            lr[k]   = bufA[v];
            bufB[v] = lr[k];    // overwrites parity slot already consumed above
        }
    }
    __syncthreads();

    // ---- sum-product BP, flooding: read RA, atomic-accumulate into RB ----
    float* RA = bufA;
    float* RB = bufB;
    for (int it = 0; it < NITER_; ++it) {
        #pragma unroll
        for (int kk = 0; kk < 5; ++kk) {
            int m = tid + 256 * kk;
            if (m < M_) {
                float tj[5];
                float P = t5[kk];
                #pragma unroll
                for (int j = 0; j < 5; ++j) {
                    float v2c = RA[vn[kk][j]] - c2vr[kk][j];
                    float av  = fminf(fmaxf(fabsf(v2c), 1e-6f), 20.0f);
                    float e   = __expf(-av);
                    float tm  = __fdividef(1.0f - e, 1.0f + e);
                    float tt  = copysignf(tm, v2c);
                    tj[j] = tt;
                    P *= tt;
                }
                #pragma unroll
                for (int j = 0; j < 5; ++j) {
                    float q = __fdividef(P, tj[j]);
                    q = fminf(fmaxf(q, -0.99999988f), 0.99999988f);
                    float r = __logf(__fdividef(1.0f + q, 1.0f - q));
                    atomicAdd(&RB[vn[kk][j]], r);
                    c2vr[kk][j] = r;
                }
            }
        }
        __syncthreads();
        // reset the just-read buffer to channel LLRs (next accumulation target)
        #pragma unroll
        for (int k = 0; k < 5; ++k) {
            int v = tid + 256 * k;
            if (v < K_) RA[v] = lr[k];
        }
        __syncthreads();
        float* t = RA; RA = RB; RB = t;
    }

    // ---- hard decision on info VNs (RA holds final lr + sum c2v) ----
    #pragma unroll
    for (int k = 0; k < 5; ++k) {
        int v = tid + 256 * k;
        if (v < K_) {
            out[(size_t)BATCH_ * K_ + b * K_ + v] = (RA[v] < 0.0f) ? 1.0f : 0.0f;
        }
    }
}

extern "C" void kernel_launch(void* const* d_in, const int* in_sizes, int n_in,
                              void* d_out, int out_size, void* d_ws, size_t ws_size,
                              hipStream_t stream) {
    const int*   bits    = (const int*)  d_in[0];
    const int*   a_idx   = (const int*)  d_in[1];
    // d_in[2] = edge_cn (implicit: contiguous groups of 6) — unused
    const int*   edge_vn = (const int*)  d_in[3];
    const float* pre     = (const float*)d_in[4];
    const float* pim     = (const float*)d_in[5];
    const float* nre     = (const float*)d_in[6];
    const float* nim     = (const float*)d_in[7];
    const float* ebno    = (const float*)d_in[8];

    link_kernel<<<BATCH_, 256, 0, stream>>>(bits, a_idx, pre, pim, nre, nim,
                                            ebno, edge_vn, (float*)d_out);
}

// Round 6
// 295.226 us; speedup vs baseline: 2.2548x; 2.2548x over previous
//
#include <hip/hip_runtime.h>

// Problem constants (match reference)
#define K_     1056
#define N_     2112
#define M_     1056   // N - K
#define E_     6336   // M * 6
#define DV_    5
#define ROW_   6      // edge 6m+5 is the parity VN K+m
#define NE_    5280   // 5*M info-side edges (the only BP state)
#define NSYM_  528
#define NITER_ 20
#define BATCH_ 1024

// -------------------------------------------------------------------------
// Build (single block): for info VNs, a degree-sorted slot permutation
// (counting sort -> waves see uniform degrees in the gather loop), compact
// CSR segment bases, and per-edge packed (vn | pos<<16) scatter targets.
// Accumulation order within a VN segment is whatever the atomics give —
// R4 empirically validated order-independence (absmax 0).
// -------------------------------------------------------------------------
__global__ __launch_bounds__(1024) void build_kernel(
    const int* __restrict__ edge_vn,
    unsigned int* __restrict__ vp,      // [M*5]: v | pos<<16
    unsigned int* __restrict__ offdeg,  // [K] slot-indexed: base | deg<<16
    int* __restrict__ perm)             // [K] slot -> v
{
    __shared__ int s_evn[E_];
    __shared__ int s_deg[K_];
    __shared__ int s_perm[K_];
    __shared__ int s_sa[K_];
    __shared__ int s_sb[K_];
    __shared__ int s_off[K_];
    __shared__ int s_cnt[K_];
    __shared__ int s_hist[32];
    const int t = threadIdx.x;

    for (int i = t; i < E_; i += 1024) s_evn[i] = edge_vn[i];
    for (int v = t; v < K_; v += 1024) { s_deg[v] = 0; s_cnt[v] = 0; }
    if (t < 32) s_hist[t] = 0;
    __syncthreads();
    for (int e = t; e < E_; e += 1024) {
        int m = e / ROW_, j = e - m * ROW_;
        if (j != 5) atomicAdd(&s_deg[s_evn[e]], 1);
    }
    __syncthreads();
    for (int v = t; v < K_; v += 1024) atomicAdd(&s_hist[s_deg[v] & 31], 1);
    __syncthreads();
    if (t == 0) {                         // exclusive scan of 32-bin histogram
        int acc = 0;
        for (int d = 0; d < 32; ++d) { int c = s_hist[d]; s_hist[d] = acc; acc += c; }
    }
    __syncthreads();
    for (int v = t; v < K_; v += 1024) {  // counting-sort: slot by degree
        int slot = atomicAdd(&s_hist[s_deg[v] & 31], 1);
        s_perm[slot] = v;
    }
    __syncthreads();
    for (int s = t; s < K_; s += 1024) s_sa[s] = s_deg[s_perm[s]];
    __syncthreads();
    int* src = s_sa; int* dst = s_sb;
    for (int off = 1; off < K_; off <<= 1) {   // Hillis-Steele inclusive scan
        for (int s = t; s < K_; s += 1024)
            dst[s] = src[s] + ((s >= off) ? src[s - off] : 0);
        __syncthreads();
        int* tmp = src; src = dst; dst = tmp;
    }
    for (int s = t; s < K_; s += 1024) {
        int v = s_perm[s];
        int d = s_deg[v];
        int base = src[s] - d;
        s_off[v] = base;
        offdeg[s] = (unsigned)base | ((unsigned)d << 16);
        perm[s] = v;
    }
    __syncthreads();
    for (int e = t; e < E_; e += 1024) {
        int m = e / ROW_, j = e - m * ROW_;
        if (j != 5) {
            int v = s_evn[e];
            int r = atomicAdd(&s_cnt[v], 1);
            unsigned pos = (unsigned)(s_off[v] + r);
            vp[m * 5 + j] = (unsigned)v | (pos << 16);
        }
    }
}

// -------------------------------------------------------------------------
// One block per codeword. LDS (29.8 KB):
//   s_tot[N]  : bits -> demapped LLRs -> per-iter info-VN marginals
//   s_c2v[NE] : info-side c2v messages, VN-major compact CSR
// Parity VNs eliminated algebraically (H=[A|I]): their v2c is always the
// channel LLR -> per-check constant tanh term t5; CN->parity msgs never
// computed. Old c2v for the extrinsic subtract is RE-READ from s_c2v
// (single writer, still intact) -> no shadow registers, no spills.
// CN math (validated in R4): t=copysign((1-e^-av)/(1+e^-av), v2c);
// P=t5*prod(t); q=clamp(P/t_j, +-0.99999988); r=log((1+q)/(1-q)).
// -------------------------------------------------------------------------
__global__ __launch_bounds__(256, 4) void link_kernel(
    const int*   __restrict__ bits,      // [B,K]
    const int*   __restrict__ a_idx,     // [M,DV]
    const float* __restrict__ points_re, // [16]
    const float* __restrict__ points_im, // [16]
    const float* __restrict__ noise_re,  // [B,NSYM]
    const float* __restrict__ noise_im,  // [B,NSYM]
    const float* __restrict__ ebno_db,   // [1]
    const unsigned int* __restrict__ vp,     // [M*5]
    const unsigned int* __restrict__ offdeg, // [K] slot-indexed
    const int*   __restrict__ perm,          // [K] slot -> v
    float*       __restrict__ out)       // [2,B,K]
{
#pragma clang fp contract(off)
    const int b   = blockIdx.x;
    const int tid = threadIdx.x;

    __shared__ float s_tot[N_];
    __shared__ float s_c2v[NE_];
    __shared__ float s_pre[16];
    __shared__ float s_pim[16];

    if (tid < 16) {
        s_pre[tid] = points_re[tid];
        s_pim[tid] = points_im[tid];
    }

    const float eb    = ebno_db[0];
    const float no    = 1.0f / ((powf(10.0f, eb / 10.0f) * 0.5f) * 4.0f);
    const float sigma = sqrtf(no / 2.0f);

    // ---- stage info bits (0/1 floats); output0 = bits.astype(f32) ----
    for (int i = tid; i < K_; i += 256) {
        int v = bits[b * K_ + i];
        s_tot[i] = (float)v;
        out[b * K_ + i] = (float)v;
    }
    __syncthreads();

    // ---- parity: XOR of DV gathered info bits ----
    for (int m = tid; m < M_; m += 256) {
        float acc = 0.0f;
        #pragma unroll
        for (int d = 0; d < DV_; ++d) acc += s_tot[a_idx[m * DV_ + d]];
        s_tot[K_ + m] = (float)(((int)acc) & 1);
    }
    __syncthreads();

    // ---- QAM map + AWGN + exact APP demap (in-place into s_tot) ----
    for (int s = tid; s < NSYM_; s += 256) {
        int c0 = (int)s_tot[4 * s + 0];
        int c1 = (int)s_tot[4 * s + 1];
        int c2 = (int)s_tot[4 * s + 2];
        int c3 = (int)s_tot[4 * s + 3];
        int sym = c0 * 8 + c1 * 4 + c2 * 2 + c3;
        float yre = s_pre[sym] + sigma * noise_re[b * NSYM_ + s];
        float yim = s_pim[sym] + sigma * noise_im[b * NSYM_ + s];
        float lg[16];
        #pragma unroll
        for (int p = 0; p < 16; ++p) {
            float dre  = yre - s_pre[p];
            float dim_ = yim - s_pim[p];
            float d2   = dre * dre + dim_ * dim_;
            lg[p] = -d2 / no;
        }
        float llr4[4];
        #pragma unroll
        for (int j = 0; j < 4; ++j) {
            float m0 = -1e30f, m1 = -1e30f;
            #pragma unroll
            for (int p = 0; p < 16; ++p) {
                if (((p >> (3 - j)) & 1) == 0) m0 = fmaxf(m0, lg[p]);
                else                           m1 = fmaxf(m1, lg[p]);
            }
            float sum0 = 0.0f, sum1 = 0.0f;
            #pragma unroll
            for (int p = 0; p < 16; ++p) {
                if (((p >> (3 - j)) & 1) == 0) sum0 += __expf(lg[p] - m0);
                else                           sum1 += __expf(lg[p] - m1);
            }
            llr4[j] = (m0 + __logf(sum0)) - (m1 + __logf(sum1));
        }
        s_tot[4 * s + 0] = llr4[0];
        s_tot[4 * s + 1] = llr4[1];
        s_tot[4 * s + 2] = llr4[2];
        s_tot[4 * s + 3] = llr4[3];
    }
    __syncthreads();

    // ---- iteration-invariant state -> registers ----
    unsigned vnp[5][5];                  // per owned check: vn | pos<<16
    float    t5[5];                      // per-check parity tanh constant
    #pragma unroll
    for (int kk = 0; kk < 5; ++kk) {
        int m = tid + 256 * kk;
        if (m < M_) {
            #pragma unroll
            for (int j = 0; j < 5; ++j) vnp[kk][j] = vp[m * 5 + j];
            float lrP = s_tot[K_ + m];
            float av  = fminf(fmaxf(fabsf(lrP), 1e-6f), 20.0f);
            float e   = __expf(-av);
            float tm  = __fdividef(1.0f - e, 1.0f + e);
            t5[kk] = copysignf(tm, lrP);
        }
    }
    int      pv[5];                      // slot -> VN id
    unsigned od[5];                      // slot segment: base | deg<<16
    float    lr[5];                      // channel LLR of owned VN
    #pragma unroll
    for (int k = 0; k < 5; ++k) {
        int s = tid + 256 * k;
        if (s < K_) {
            pv[k] = perm[s];
            od[k] = offdeg[s];
            lr[k] = s_tot[pv[k]];
        }
    }
    for (int i = tid; i < NE_; i += 256) s_c2v[i] = 0.0f;
    __syncthreads();

    // ---- sum-product BP, flooding ----
    for (int it = 0; it < NITER_; ++it) {
        // Phase A: marginals of info VNs (degree-sorted -> wave-uniform trip)
        #pragma unroll
        for (int k = 0; k < 5; ++k) {
            int s = tid + 256 * k;
            if (s < K_) {
                int base = (int)(od[k] & 0xFFFFu);
                int dg   = (int)(od[k] >> 16);
                float mg = lr[k];
                for (int d = 0; d < dg; ++d) mg += s_c2v[base + d];
                s_tot[pv[k]] = mg;
            }
        }
        __syncthreads();
        // Phase B: CN update, product form; old c2v re-read from s_c2v
        #pragma unroll
        for (int kk = 0; kk < 5; ++kk) {
            int m = tid + 256 * kk;
            if (m < M_) {
                float tj[5];
                float P = t5[kk];
                #pragma unroll
                for (int j = 0; j < 5; ++j) {
                    unsigned w = vnp[kk][j];
                    float v2c = s_tot[w & 0xFFFFu] - s_c2v[w >> 16];
                    float av  = fminf(fmaxf(fabsf(v2c), 1e-6f), 20.0f);
                    float e   = __expf(-av);
                    float tm  = __fdividef(1.0f - e, 1.0f + e);
                    float tt  = copysignf(tm, v2c);
                    tj[j] = tt;
                    P *= tt;
                }
                #pragma unroll
                for (int j = 0; j < 5; ++j) {
                    float q = __fdividef(P, tj[j]);
                    q = fminf(fmaxf(q, -0.99999988f), 0.99999988f);
                    float r = __logf(__fdividef(1.0f + q, 1.0f - q));
                    s_c2v[vnp[kk][j] >> 16] = r;
                }
            }
        }
        __syncthreads();
    }

    // ---- final marginal + hard decision on info VNs ----
    #pragma unroll
    for (int k = 0; k < 5; ++k) {
        int s = tid + 256 * k;
        if (s < K_) {
            int base = (int)(od[k] & 0xFFFFu);
            int dg   = (int)(od[k] >> 16);
            float mg = lr[k];
            for (int d = 0; d < dg; ++d) mg += s_c2v[base + d];
            out[(size_t)BATCH_ * K_ + b * K_ + pv[k]] = (mg < 0.0f) ? 1.0f : 0.0f;
        }
    }
}

extern "C" void kernel_launch(void* const* d_in, const int* in_sizes, int n_in,
                              void* d_out, int out_size, void* d_ws, size_t ws_size,
                              hipStream_t stream) {
    const int*   bits    = (const int*)  d_in[0];
    const int*   a_idx   = (const int*)  d_in[1];
    // d_in[2] = edge_cn (implicit: contiguous groups of 6) — unused
    const int*   edge_vn = (const int*)  d_in[3];
    const float* pre     = (const float*)d_in[4];
    const float* pim     = (const float*)d_in[5];
    const float* nre     = (const float*)d_in[6];
    const float* nim     = (const float*)d_in[7];
    const float* ebno    = (const float*)d_in[8];

    char* ws = (char*)d_ws;
    unsigned int* vp     = (unsigned int*)ws;  ws += (size_t)M_ * 5 * sizeof(unsigned int);
    unsigned int* offdeg = (unsigned int*)ws;  ws += (size_t)K_ * sizeof(unsigned int);
    int*          perm   = (int*)ws;

    build_kernel<<<1, 1024, 0, stream>>>(edge_vn, vp, offdeg, perm);
    link_kernel<<<BATCH_, 256, 0, stream>>>(bits, a_idx, pre, pim, nre, nim,
                                            ebno, vp, offdeg, perm, (float*)d_out);
}

// Round 7
// 269.285 us; speedup vs baseline: 2.4720x; 1.0963x over previous
//
#include <hip/hip_runtime.h>

// Problem constants (match reference)
#define K_     1056
#define N_     2112
#define M_     1056   // N - K
#define E_     6336   // M * 6
#define NIE_   5280   // M * 5 info-side edges (the only BP state)
#define DV_    5
#define ROW_   6      // edge 6m+5 is the parity VN K+m
#define NSYM_  528
#define NITER_ 20
#define BATCH_ 1024

// ---- build pipeline (parallelized; atomic order nondeterminism only
//      permutes float accumulation order — validated safe in R4/R5) ----

__global__ __launch_bounds__(256) void zero_kernel(int* __restrict__ deg,
                                                   int* __restrict__ cnt) {
    int i = blockIdx.x * 256 + threadIdx.x;
    if (i < K_) { deg[i] = 0; cnt[i] = 0; }
}

// degree of each info VN (info-side edges only)
__global__ __launch_bounds__(256) void deg_kernel(const int* __restrict__ edge_vn,
                                                  int* __restrict__ deg) {
    int idx = blockIdx.x * 256 + threadIdx.x;
    if (idx >= NIE_) return;
    int m = idx / 5, j = idx - m * 5;
    atomicAdd(&deg[edge_vn[m * ROW_ + j]], 1);
}

// single block, K-scale only: counting-sort VNs by degree (wave-uniform
// gather trip counts in Phase A) + segment base offsets
__global__ __launch_bounds__(1024) void sort_kernel(
    const int* __restrict__ deg,
    unsigned int* __restrict__ offdeg,  // [K] slot-indexed: base | deg<<16
    int* __restrict__ perm,             // [K] slot -> v
    int* __restrict__ voff)             // [K] v -> segment base
{
    __shared__ int s_deg[K_];
    __shared__ int s_perm[K_];
    __shared__ int s_sa[K_];
    __shared__ int s_sb[K_];
    __shared__ int s_hist[32];
    const int t = threadIdx.x;

    for (int v = t; v < K_; v += 1024) s_deg[v] = deg[v];
    if (t < 32) s_hist[t] = 0;
    __syncthreads();
    for (int v = t; v < K_; v += 1024) atomicAdd(&s_hist[s_deg[v] & 31], 1);
    __syncthreads();
    if (t == 0) {
        int acc = 0;
        for (int d = 0; d < 32; ++d) { int c = s_hist[d]; s_hist[d] = acc; acc += c; }
    }
    __syncthreads();
    for (int v = t; v < K_; v += 1024) {
        int slot = atomicAdd(&s_hist[s_deg[v] & 31], 1);
        s_perm[slot] = v;
    }
    __syncthreads();
    for (int s = t; s < K_; s += 1024) s_sa[s] = s_deg[s_perm[s]];
    __syncthreads();
    int* src = s_sa; int* dst = s_sb;
    for (int off = 1; off < K_; off <<= 1) {   // Hillis-Steele inclusive scan
        for (int s = t; s < K_; s += 1024)
            dst[s] = src[s] + ((s >= off) ? src[s - off] : 0);
        __syncthreads();
        int* tmp = src; src = dst; dst = tmp;
    }
    for (int s = t; s < K_; s += 1024) {
        int v = s_perm[s];
        int d = s_deg[v];
        int base = src[s] - d;
        offdeg[s] = (unsigned)base | ((unsigned)d << 16);
        perm[s] = v;
        voff[v] = base;
    }
}

// per-edge packed scatter target: vp[m*5+j] = vn | pos<<16
__global__ __launch_bounds__(256) void pos_kernel(
    const int* __restrict__ edge_vn,
    const int* __restrict__ voff,
    int* __restrict__ cnt,
    unsigned int* __restrict__ vp) {
    int idx = blockIdx.x * 256 + threadIdx.x;
    if (idx >= NIE_) return;
    int m = idx / 5, j = idx - m * 5;
    int v = edge_vn[m * ROW_ + j];
    int r = atomicAdd(&cnt[v], 1);
    vp[idx] = (unsigned)v | ((unsigned)(voff[v] + r) << 16);
}

// -------------------------------------------------------------------------
// One block per codeword. LDS (29.8 KB -> 4 blocks/CU):
//   s_tot[N]   : bits -> demapped LLRs -> per-iter info-VN marginals
//   s_c2v[NIE] : info-side c2v messages, VN-major compact CSR
// Parity VNs eliminated algebraically (H=[A|I]): per-check constant tanh
// term t5; CN->parity msgs never computed. Old c2v re-read from s_c2v.
// CN math (product form, prefix/suffix partial products — no q divide):
//   t = copysign((1-e^-av)/(1+e^-av), v2c);  q_j = t5 * prod_{i!=j} t_i
//   q clamped to +-0.99999988;  r = log((1+q)/(1-q))
// -------------------------------------------------------------------------
__global__ __launch_bounds__(256, 4) void link_kernel(
    const int*   __restrict__ bits,      // [B,K]
    const int*   __restrict__ a_idx,     // [M,DV]
    const float* __restrict__ points_re, // [16]
    const float* __restrict__ points_im, // [16]
    const float* __restrict__ noise_re,  // [B,NSYM]
    const float* __restrict__ noise_im,  // [B,NSYM]
    const float* __restrict__ ebno_db,   // [1]
    const unsigned int* __restrict__ vp,     // [M*5]
    const unsigned int* __restrict__ offdeg, // [K] slot-indexed
    const int*   __restrict__ perm,          // [K] slot -> v
    float*       __restrict__ out)       // [2,B,K]
{
#pragma clang fp contract(off)
    const int b   = blockIdx.x;
    const int tid = threadIdx.x;

    __shared__ float s_tot[N_];
    __shared__ float s_c2v[NIE_];
    __shared__ float s_pre[16];
    __shared__ float s_pim[16];

    if (tid < 16) {
        s_pre[tid] = points_re[tid];
        s_pim[tid] = points_im[tid];
    }

    const float eb    = ebno_db[0];
    const float no    = 1.0f / ((powf(10.0f, eb / 10.0f) * 0.5f) * 4.0f);
    const float sigma = sqrtf(no / 2.0f);

    // ---- stage info bits (0/1 floats); output0 = bits.astype(f32) ----
    for (int i = tid; i < K_; i += 256) {
        int v = bits[b * K_ + i];
        s_tot[i] = (float)v;
        out[b * K_ + i] = (float)v;
    }
    __syncthreads();

    // ---- parity: XOR of DV gathered info bits ----
    for (int m = tid; m < M_; m += 256) {
        float acc = 0.0f;
        #pragma unroll
        for (int d = 0; d < DV_; ++d) acc += s_tot[a_idx[m * DV_ + d]];
        s_tot[K_ + m] = (float)(((int)acc) & 1);
    }
    __syncthreads();

    // ---- QAM map + AWGN + exact APP demap (in-place into s_tot) ----
    for (int s = tid; s < NSYM_; s += 256) {
        int c0 = (int)s_tot[4 * s + 0];
        int c1 = (int)s_tot[4 * s + 1];
        int c2 = (int)s_tot[4 * s + 2];
        int c3 = (int)s_tot[4 * s + 3];
        int sym = c0 * 8 + c1 * 4 + c2 * 2 + c3;
        float yre = s_pre[sym] + sigma * noise_re[b * NSYM_ + s];
        float yim = s_pim[sym] + sigma * noise_im[b * NSYM_ + s];
        float lg[16];
        #pragma unroll
        for (int p = 0; p < 16; ++p) {
            float dre  = yre - s_pre[p];
            float dim_ = yim - s_pim[p];
            float d2   = dre * dre + dim_ * dim_;
            lg[p] = -d2 / no;
        }
        float llr4[4];
        #pragma unroll
        for (int j = 0; j < 4; ++j) {
            float m0 = -1e30f, m1 = -1e30f;
            #pragma unroll
            for (int p = 0; p < 16; ++p) {
                if (((p >> (3 - j)) & 1) == 0) m0 = fmaxf(m0, lg[p]);
                else                           m1 = fmaxf(m1, lg[p]);
            }
            float sum0 = 0.0f, sum1 = 0.0f;
            #pragma unroll
            for (int p = 0; p < 16; ++p) {
                if (((p >> (3 - j)) & 1) == 0) sum0 += __expf(lg[p] - m0);
                else                           sum1 += __expf(lg[p] - m1);
            }
            llr4[j] = (m0 + __logf(sum0)) - (m1 + __logf(sum1));
        }
        s_tot[4 * s + 0] = llr4[0];
        s_tot[4 * s + 1] = llr4[1];
        s_tot[4 * s + 2] = llr4[2];
        s_tot[4 * s + 3] = llr4[3];
    }
    __syncthreads();

    // ---- iteration-invariant state -> registers ----
    unsigned vnp[5][5];                  // per owned check: vn | pos<<16
    float    t5[5];                      // per-check parity tanh constant
    #pragma unroll
    for (int kk = 0; kk < 5; ++kk) {
        int m = tid + 256 * kk;
        if (m < M_) {
            #pragma unroll
            for (int j = 0; j < 5; ++j) vnp[kk][j] = vp[m * 5 + j];
            float lrP = s_tot[K_ + m];
            float av  = fminf(fmaxf(fabsf(lrP), 1e-6f), 20.0f);
            float e   = __expf(-av);
            float tm  = __fdividef(1.0f - e, 1.0f + e);
            t5[kk] = copysignf(tm, lrP);
        }
    }
    int      pv[5];                      // slot -> VN id
    unsigned od[5];                      // slot segment: base | deg<<16
    float    lr[5];                      // channel LLR of owned VN
    #pragma unroll
    for (int k = 0; k < 5; ++k) {
        int s = tid + 256 * k;
        if (s < K_) {
            pv[k] = perm[s];
            od[k] = offdeg[s];
            lr[k] = s_tot[pv[k]];
        }
    }
    for (int i = tid; i < NIE_; i += 256) s_c2v[i] = 0.0f;
    __syncthreads();

    // ---- sum-product BP, flooding ----
    for (int it = 0; it < NITER_; ++it) {
        // Phase A: marginals of info VNs (degree-sorted -> wave-uniform trip)
        #pragma unroll
        for (int k = 0; k < 5; ++k) {
            int s = tid + 256 * k;
            if (s < K_) {
                int base = (int)(od[k] & 0xFFFFu);
                int dg   = (int)(od[k] >> 16);
                float mg = lr[k];
                for (int d = 0; d < dg; ++d) mg += s_c2v[base + d];
                s_tot[pv[k]] = mg;
            }
        }
        __syncthreads();
        // Phase B: CN update, prefix/suffix products (no divide for q)
        #pragma unroll
        for (int kk = 0; kk < 5; ++kk) {
            int m = tid + 256 * kk;
            if (m < M_) {
                float tj[5];
                #pragma unroll
                for (int j = 0; j < 5; ++j) {
                    unsigned w = vnp[kk][j];
                    float v2c = s_tot[w & 0xFFFFu] - s_c2v[w >> 16];
                    float av  = fminf(fmaxf(fabsf(v2c), 1e-6f), 20.0f);
                    float e   = __expf(-av);
                    float tm  = __fdividef(1.0f - e, 1.0f + e);
                    tj[j] = copysignf(tm, v2c);
                }
                float qv[5];
                float pr = t5[kk];
                #pragma unroll
                for (int j = 0; j < 5; ++j) { qv[j] = pr; pr *= tj[j]; }
                float sf = 1.0f;
                #pragma unroll
                for (int j = 4; j >= 0; --j) { qv[j] *= sf; sf *= tj[j]; }
                #pragma unroll
                for (int j = 0; j < 5; ++j) {
                    float q = fminf(fmaxf(qv[j], -0.99999988f), 0.99999988f);
                    float r = __logf(__fdividef(1.0f + q, 1.0f - q));
                    s_c2v[vnp[kk][j] >> 16] = r;
                }
            }
        }
        __syncthreads();
    }

    // ---- final marginal + hard decision on info VNs ----
    #pragma unroll
    for (int k = 0; k < 5; ++k) {
        int s = tid + 256 * k;
        if (s < K_) {
            int base = (int)(od[k] & 0xFFFFu);
            int dg   = (int)(od[k] >> 16);
            float mg = lr[k];
            for (int d = 0; d < dg; ++d) mg += s_c2v[base + d];
            out[(size_t)BATCH_ * K_ + b * K_ + pv[k]] = (mg < 0.0f) ? 1.0f : 0.0f;
        }
    }
}

extern "C" void kernel_launch(void* const* d_in, const int* in_sizes, int n_in,
                              void* d_out, int out_size, void* d_ws, size_t ws_size,
                              hipStream_t stream) {
    const int*   bits    = (const int*)  d_in[0];
    const int*   a_idx   = (const int*)  d_in[1];
    // d_in[2] = edge_cn (implicit: contiguous groups of 6) — unused
    const int*   edge_vn = (const int*)  d_in[3];
    const float* pre     = (const float*)d_in[4];
    const float* pim     = (const float*)d_in[5];
    const float* nre     = (const float*)d_in[6];
    const float* nim     = (const float*)d_in[7];
    const float* ebno    = (const float*)d_in[8];

    char* ws = (char*)d_ws;
    unsigned int* vp     = (unsigned int*)ws;  ws += (size_t)NIE_ * sizeof(unsigned int);
    unsigned int* offdeg = (unsigned int*)ws;  ws += (size_t)K_ * sizeof(unsigned int);
    int*          perm   = (int*)ws;           ws += (size_t)K_ * sizeof(int);
    int*          voff   = (int*)ws;           ws += (size_t)K_ * sizeof(int);
    int*          deg    = (int*)ws;           ws += (size_t)K_ * sizeof(int);
    int*          cnt    = (int*)ws;

    zero_kernel<<<(K_ + 255) / 256, 256, 0, stream>>>(deg, cnt);
    deg_kernel<<<(NIE_ + 255) / 256, 256, 0, stream>>>(edge_vn, deg);
    sort_kernel<<<1, 1024, 0, stream>>>(deg, offdeg, perm, voff);
    pos_kernel<<<(NIE_ + 255) / 256, 256, 0, stream>>>(edge_vn, voff, cnt, vp);
    link_kernel<<<BATCH_, 256, 0, stream>>>(bits, a_idx, pre, pim, nre, nim,
                                            ebno, vp, offdeg, perm, (float*)d_out);
}

// Round 8
// 267.900 us; speedup vs baseline: 2.4848x; 1.0052x over previous
//
#include <hip/hip_runtime.h>

// Problem constants (match reference)
#define K_     1056
#define N_     2112
#define M_     1056   // N - K
#define E_     6336   // M * 6
#define NIE_   5280   // M * 5 info-side edges (the only BP state)
#define DV_    5
#define ROW_   6      // edge 6m+5 is the parity VN K+m
#define NSYM_  528
#define NITER_ 20
#define BATCH_ 1024

// -------------------------------------------------------------------------
// Single kernel, one block per codeword. Each block builds its own compact
// VN-major CSR in LDS (one-time, ~16K LDS ops) — zero extra dispatches.
//
// LDS (29.7 KB -> 4 blocks/CU):
//   s_tot[N]   : bits -> demapped LLRs -> per-iter info-VN marginals
//   s_c2v[NIE] : int scratch during build (deg|perm|sa|sb|off = 5*1056),
//                then info-side c2v messages, VN-major compact CSR
//
// Structure exploited: H = [A | I].
//   * Parity VN (deg 1): v2c == channel LLR always -> per-check constant
//     tanh term t5; CN->parity messages never computed.
//   * Info VNs counting-sorted by degree -> wave-uniform Phase A trip count.
//   * Per-block atomic build order only permutes float accumulation order —
//     validated order-independent in R4/R5/R6 (absmax 0).
//
// CN math (product form, prefix/suffix partial products — no q divide):
//   t = copysign((1-e^-av)/(1+e^-av), v2c);  q_j = t5 * prod_{i!=j} t_i
//   q clamped to +-0.99999988;  r = log((1+q)/(1-q))
// -------------------------------------------------------------------------
__global__ __launch_bounds__(256, 4) void link_kernel(
    const int*   __restrict__ bits,      // [B,K]
    const int*   __restrict__ a_idx,     // [M,DV]
    const float* __restrict__ points_re, // [16]
    const float* __restrict__ points_im, // [16]
    const float* __restrict__ noise_re,  // [B,NSYM]
    const float* __restrict__ noise_im,  // [B,NSYM]
    const float* __restrict__ ebno_db,   // [1]
    const int*   __restrict__ edge_vn,   // [E]
    float*       __restrict__ out)       // [2,B,K]
{
#pragma clang fp contract(off)
    const int b   = blockIdx.x;
    const int tid = threadIdx.x;

    __shared__ float s_tot[N_];
    __shared__ float s_c2v[NIE_];
    __shared__ float s_pre[16];
    __shared__ float s_pim[16];
    __shared__ int   s_hist[32];

    if (tid < 16) {
        s_pre[tid] = points_re[tid];
        s_pim[tid] = points_im[tid];
    }
    if (tid < 32) s_hist[tid] = 0;

    const float eb    = ebno_db[0];
    const float no    = 1.0f / ((powf(10.0f, eb / 10.0f) * 0.5f) * 4.0f);
    const float sigma = sqrtf(no / 2.0f);

    // ---- stage info bits (0/1 floats); output0 = bits.astype(f32) ----
    for (int i = tid; i < K_; i += 256) {
        int v = bits[b * K_ + i];
        s_tot[i] = (float)v;
        out[b * K_ + i] = (float)v;
    }
    __syncthreads();

    // ---- parity: XOR of DV gathered info bits ----
    for (int m = tid; m < M_; m += 256) {
        float acc = 0.0f;
        #pragma unroll
        for (int d = 0; d < DV_; ++d) acc += s_tot[a_idx[m * DV_ + d]];
        s_tot[K_ + m] = (float)(((int)acc) & 1);
    }
    __syncthreads();

    // ---- QAM map + AWGN + exact APP demap (in-place into s_tot) ----
    for (int s = tid; s < NSYM_; s += 256) {
        int c0 = (int)s_tot[4 * s + 0];
        int c1 = (int)s_tot[4 * s + 1];
        int c2 = (int)s_tot[4 * s + 2];
        int c3 = (int)s_tot[4 * s + 3];
        int sym = c0 * 8 + c1 * 4 + c2 * 2 + c3;
        float yre = s_pre[sym] + sigma * noise_re[b * NSYM_ + s];
        float yim = s_pim[sym] + sigma * noise_im[b * NSYM_ + s];
        float lg[16];
        #pragma unroll
        for (int p = 0; p < 16; ++p) {
            float dre  = yre - s_pre[p];
            float dim_ = yim - s_pim[p];
            float d2   = dre * dre + dim_ * dim_;
            lg[p] = -d2 / no;
        }
        float llr4[4];
        #pragma unroll
        for (int j = 0; j < 4; ++j) {
            float m0 = -1e30f, m1 = -1e30f;
            #pragma unroll
            for (int p = 0; p < 16; ++p) {
                if (((p >> (3 - j)) & 1) == 0) m0 = fmaxf(m0, lg[p]);
                else                           m1 = fmaxf(m1, lg[p]);
            }
            float sum0 = 0.0f, sum1 = 0.0f;
            #pragma unroll
            for (int p = 0; p < 16; ++p) {
                if (((p >> (3 - j)) & 1) == 0) sum0 += __expf(lg[p] - m0);
                else                           sum1 += __expf(lg[p] - m1);
            }
            llr4[j] = (m0 + __logf(sum0)) - (m1 + __logf(sum1));
        }
        s_tot[4 * s + 0] = llr4[0];
        s_tot[4 * s + 1] = llr4[1];
        s_tot[4 * s + 2] = llr4[2];
        s_tot[4 * s + 3] = llr4[3];
    }

    // ================= in-block CSR build (s_c2v as int scratch) ==========
    int* sc     = (int*)s_c2v;           // 5280 ints total
    int* s_deg  = sc;                    // [K]  degree, later reused as cnt
    int* s_perm = sc + K_;               // [K]  slot -> v
    int* s_sa   = sc + 2 * K_;           // [K]  scan ping
    int* s_sb   = sc + 3 * K_;           // [K]  scan pong
    int* s_off  = sc + 4 * K_;           // [K]  v -> segment base

    for (int v = tid; v < K_; v += 256) s_deg[v] = 0;
    __syncthreads();
    // degree count over info-side edges
    for (int idx = tid; idx < NIE_; idx += 256) {
        int m = idx / 5, j = idx - m * 5;
        atomicAdd(&s_deg[edge_vn[m * ROW_ + j]], 1);
    }
    __syncthreads();
    // 32-bin degree histogram
    for (int v = tid; v < K_; v += 256) atomicAdd(&s_hist[s_deg[v] & 31], 1);
    __syncthreads();
    if (tid == 0) {                      // exclusive scan of histogram
        int acc = 0;
        for (int d = 0; d < 32; ++d) { int c = s_hist[d]; s_hist[d] = acc; acc += c; }
    }
    __syncthreads();
    // counting sort: slot by degree (order within a bin nondeterministic; OK)
    for (int v = tid; v < K_; v += 256) {
        int slot = atomicAdd(&s_hist[s_deg[v] & 31], 1);
        s_perm[slot] = v;
    }
    __syncthreads();
    for (int s = tid; s < K_; s += 256) s_sa[s] = s_deg[s_perm[s]];
    __syncthreads();
    int* src = s_sa; int* dst = s_sb;
    for (int off = 1; off < K_; off <<= 1) {   // Hillis-Steele inclusive scan
        for (int s = tid; s < K_; s += 256)
            dst[s] = src[s] + ((s >= off) ? src[s - off] : 0);
        __syncthreads();
        int* tmp = src; src = dst; dst = tmp;
    }
    // slot-owner registers + v->base map
    int      pv[5];                      // slot -> VN id
    unsigned od[5];                      // base | deg<<16
    float    lr[5];                      // channel LLR of owned VN
    {
        int k = 0;
        for (int s = tid; s < K_; s += 256, ++k) {
            int v = s_perm[s];
            int d = s_deg[v];
            int base = src[s] - d;
            pv[k] = v;
            od[k] = (unsigned)base | ((unsigned)d << 16);
            s_off[v] = base;
            lr[k] = s_tot[v];            // demap done (barrier above)
        }
        for (; k < 5; ++k) { pv[k] = 0; od[k] = 0; lr[k] = 0.0f; }
    }
    __syncthreads();
    for (int v = tid; v < K_; v += 256) s_deg[v] = 0;   // reuse deg as cnt
    __syncthreads();
    // per-check edge targets (vn | pos<<16) + parity tanh constant t5
    unsigned vnp[5][5];
    float    t5[5];
    #pragma unroll
    for (int kk = 0; kk < 5; ++kk) {
        int m = tid + 256 * kk;
        if (m < M_) {
            #pragma unroll
            for (int j = 0; j < 5; ++j) {
                int v = edge_vn[m * ROW_ + j];
                int r = atomicAdd(&s_deg[v], 1);
                vnp[kk][j] = (unsigned)v | ((unsigned)(s_off[v] + r) << 16);
            }
            float lrP = s_tot[K_ + m];
            float av  = fminf(fmaxf(fabsf(lrP), 1e-6f), 20.0f);
            float e   = __expf(-av);
            float tm  = __fdividef(1.0f - e, 1.0f + e);
            t5[kk] = copysignf(tm, lrP);
        }
    }
    __syncthreads();
    // scratch fully consumed -> become the message array
    for (int i = tid; i < NIE_; i += 256) s_c2v[i] = 0.0f;
    __syncthreads();
    // ======================================================================

    // ---- sum-product BP, flooding ----
    for (int it = 0; it < NITER_; ++it) {
        // Phase A: marginals of info VNs (degree-sorted -> wave-uniform trip)
        #pragma unroll
        for (int k = 0; k < 5; ++k) {
            int s = tid + 256 * k;
            if (s < K_) {
                int base = (int)(od[k] & 0xFFFFu);
                int dg   = (int)(od[k] >> 16);
                float mg = lr[k];
                for (int d = 0; d < dg; ++d) mg += s_c2v[base + d];
                s_tot[pv[k]] = mg;
            }
        }
        __syncthreads();
        // Phase B: CN update, prefix/suffix products (no divide for q)
        #pragma unroll
        for (int kk = 0; kk < 5; ++kk) {
            int m = tid + 256 * kk;
            if (m < M_) {
                float tj[5];
                #pragma unroll
                for (int j = 0; j < 5; ++j) {
                    unsigned w = vnp[kk][j];
                    float v2c = s_tot[w & 0xFFFFu] - s_c2v[w >> 16];
                    float av  = fminf(fmaxf(fabsf(v2c), 1e-6f), 20.0f);
                    float e   = __expf(-av);
                    float tm  = __fdividef(1.0f - e, 1.0f + e);
                    tj[j] = copysignf(tm, v2c);
                }
                float qv[5];
                float pr = t5[kk];
                #pragma unroll
                for (int j = 0; j < 5; ++j) { qv[j] = pr; pr *= tj[j]; }
                float sf = 1.0f;
                #pragma unroll
                for (int j = 4; j >= 0; --j) { qv[j] *= sf; sf *= tj[j]; }
                #pragma unroll
                for (int j = 0; j < 5; ++j) {
                    float q = fminf(fmaxf(qv[j], -0.99999988f), 0.99999988f);
                    float r = __logf(__fdividef(1.0f + q, 1.0f - q));
                    s_c2v[vnp[kk][j] >> 16] = r;
                }
            }
        }
        __syncthreads();
    }

    // ---- final marginal + hard decision on info VNs ----
    #pragma unroll
    for (int k = 0; k < 5; ++k) {
        int s = tid + 256 * k;
        if (s < K_) {
            int base = (int)(od[k] & 0xFFFFu);
            int dg   = (int)(od[k] >> 16);
            float mg = lr[k];
            for (int d = 0; d < dg; ++d) mg += s_c2v[base + d];
            out[(size_t)BATCH_ * K_ + b * K_ + pv[k]] = (mg < 0.0f) ? 1.0f : 0.0f;
        }
    }
}

extern "C" void kernel_launch(void* const* d_in, const int* in_sizes, int n_in,
                              void* d_out, int out_size, void* d_ws, size_t ws_size,
                              hipStream_t stream) {
    const int*   bits    = (const int*)  d_in[0];
    const int*   a_idx   = (const int*)  d_in[1];
    // d_in[2] = edge_cn (implicit: contiguous groups of 6) — unused
    const int*   edge_vn = (const int*)  d_in[3];
    const float* pre     = (const float*)d_in[4];
    const float* pim     = (const float*)d_in[5];
    const float* nre     = (const float*)d_in[6];
    const float* nim     = (const float*)d_in[7];
    const float* ebno    = (const float*)d_in[8];

    link_kernel<<<BATCH_, 256, 0, stream>>>(bits, a_idx, pre, pim, nre, nim,
                                            ebno, edge_vn, (float*)d_out);
}

// Round 9
// 260.410 us; speedup vs baseline: 2.5562x; 1.0288x over previous
//
#include <hip/hip_runtime.h>

// Problem constants (match reference)
#define K_     1056
#define N_     2112
#define M_     1056   // N - K
#define E_     6336   // M * 6
#define NIE_   5280   // M * 5 info-side edges (the only BP state)
#define CAP_   7392   // NIE_ + 2*K worst-case odd-stride padding
#define DV_    5
#define ROW_   6      // edge 6m+5 is the parity VN K+m
#define NSYM_  528
#define NITER_ 20
#define BATCH_ 1024

// stride(d) = d + 1 (d even) or d + 2 (d odd)  -> always ODD -> coprime with
// the 32 LDS banks -> Phase A's wave-uniform-stride segment reads are
// conflict-free.
__device__ __forceinline__ int seg_stride(int d) { return d + 1 + (d & 1); }

// -------------------------------------------------------------------------
// Single kernel, one block per codeword. Each block builds its own compact
// VN-major CSR in LDS (scan-free: histogram arithmetic gives segment bases).
//
// LDS (~38.7 KB -> 4 blocks/CU):
//   s_tot[N]   : bits -> demapped LLRs (VN-indexed); then BP marginals
//                (SLOT-indexed, stride-1 writes, first K entries)
//   s_c2v[CAP] : int scratch during build (deg|perm|offslot|cnt = 4*1056),
//                then c2v messages in odd-stride padded VN-major segments
//
// Structure exploited: H = [A | I].
//   * Parity VN (deg 1): v2c == channel LLR -> per-check constant t5;
//     CN->parity messages never computed.
//   * Info VNs counting-sorted by degree -> wave-uniform Phase A trips.
//   * Old c2v kept in registers (c2vr) -> no LDS re-read in Phase B.
//   * Atomic build order only permutes float accumulation order —
//     validated order-independent in R4-R7 (absmax 0).
//
// CN math (product form, prefix/suffix partial products):
//   t = copysign((1-e^-av)/(1+e^-av), v2c);  q_j = t5 * prod_{i!=j} t_i
//   q clamped to +-0.99999988;  r = log((1+q)/(1-q))
// -------------------------------------------------------------------------
__global__ __launch_bounds__(256, 4) void link_kernel(
    const int*   __restrict__ bits,      // [B,K]
    const int*   __restrict__ a_idx,     // [M,DV]
    const float* __restrict__ points_re, // [16]
    const float* __restrict__ points_im, // [16]
    const float* __restrict__ noise_re,  // [B,NSYM]
    const float* __restrict__ noise_im,  // [B,NSYM]
    const float* __restrict__ ebno_db,   // [1]
    const int*   __restrict__ edge_vn,   // [E]
    float*       __restrict__ out)       // [2,B,K]
{
#pragma clang fp contract(off)
    const int b   = blockIdx.x;
    const int tid = threadIdx.x;

    __shared__ float s_tot[N_];
    __shared__ float s_c2v[CAP_];
    __shared__ float s_pre[16];
    __shared__ float s_pim[16];
    __shared__ int   s_hist[32];
    __shared__ int   s_binStart[32];
    __shared__ int   s_binBase[32];

    if (tid < 16) {
        s_pre[tid] = points_re[tid];
        s_pim[tid] = points_im[tid];
    }
    if (tid < 32) s_hist[tid] = 0;

    const float eb    = ebno_db[0];
    const float no    = 1.0f / ((powf(10.0f, eb / 10.0f) * 0.5f) * 4.0f);
    const float sigma = sqrtf(no / 2.0f);

    // ---- stage info bits (0/1 floats); output0 = bits.astype(f32) ----
    for (int i = tid; i < K_; i += 256) {
        int v = bits[b * K_ + i];
        s_tot[i] = (float)v;
        out[b * K_ + i] = (float)v;
    }
    __syncthreads();

    // ---- parity: XOR of DV gathered info bits ----
    for (int m = tid; m < M_; m += 256) {
        float acc = 0.0f;
        #pragma unroll
        for (int d = 0; d < DV_; ++d) acc += s_tot[a_idx[m * DV_ + d]];
        s_tot[K_ + m] = (float)(((int)acc) & 1);
    }
    __syncthreads();

    // ---- QAM map + AWGN + exact APP demap (in-place into s_tot) ----
    for (int s = tid; s < NSYM_; s += 256) {
        int c0 = (int)s_tot[4 * s + 0];
        int c1 = (int)s_tot[4 * s + 1];
        int c2 = (int)s_tot[4 * s + 2];
        int c3 = (int)s_tot[4 * s + 3];
        int sym = c0 * 8 + c1 * 4 + c2 * 2 + c3;
        float yre = s_pre[sym] + sigma * noise_re[b * NSYM_ + s];
        float yim = s_pim[sym] + sigma * noise_im[b * NSYM_ + s];
        float lg[16];
        #pragma unroll
        for (int p = 0; p < 16; ++p) {
            float dre  = yre - s_pre[p];
            float dim_ = yim - s_pim[p];
            float d2   = dre * dre + dim_ * dim_;
            lg[p] = -d2 / no;
        }
        float llr4[4];
        #pragma unroll
        for (int j = 0; j < 4; ++j) {
            float m0 = -1e30f, m1 = -1e30f;
            #pragma unroll
            for (int p = 0; p < 16; ++p) {
                if (((p >> (3 - j)) & 1) == 0) m0 = fmaxf(m0, lg[p]);
                else                           m1 = fmaxf(m1, lg[p]);
            }
            float sum0 = 0.0f, sum1 = 0.0f;
            #pragma unroll
            for (int p = 0; p < 16; ++p) {
                if (((p >> (3 - j)) & 1) == 0) sum0 += __expf(lg[p] - m0);
                else                           sum1 += __expf(lg[p] - m1);
            }
            llr4[j] = (m0 + __logf(sum0)) - (m1 + __logf(sum1));
        }
        s_tot[4 * s + 0] = llr4[0];
        s_tot[4 * s + 1] = llr4[1];
        s_tot[4 * s + 2] = llr4[2];
        s_tot[4 * s + 3] = llr4[3];
    }

    // ================= in-block CSR build (s_c2v as int scratch) ==========
    int* sc        = (int*)s_c2v;        // 4*1056 = 4224 ints <= CAP_
    int* s_deg     = sc;                 // [K] degree
    int* s_perm    = sc + K_;            // [K] slot -> v | deg<<16
    int* s_offslot = sc + 2 * K_;        // [K] v -> base | slot<<16
    int* s_cnt     = sc + 3 * K_;        // [K] edge-fill cursors

    for (int v = tid; v < K_; v += 256) { s_deg[v] = 0; s_cnt[v] = 0; }
    __syncthreads();
    // degree count; edge_vn cached in registers for the later vnp pass
    int ev[5][5];
    #pragma unroll
    for (int kk = 0; kk < 5; ++kk) {
        int m = tid + 256 * kk;
        if (m < M_) {
            #pragma unroll
            for (int j = 0; j < 5; ++j) {
                ev[kk][j] = edge_vn[m * ROW_ + j];
                atomicAdd(&s_deg[ev[kk][j]], 1);
            }
        }
    }
    __syncthreads();
    for (int v = tid; v < K_; v += 256) atomicAdd(&s_hist[s_deg[v] & 31], 1);
    __syncthreads();
    if (tid == 0) {                      // histogram prefix -> starts & bases
        int accS = 0, accB = 0;
        for (int d = 0; d < 32; ++d) {
            int c = s_hist[d];
            s_binStart[d] = accS;
            s_binBase[d]  = accB;
            s_hist[d]     = accS;        // reuse as sort cursor
            accS += c;
            accB += c * seg_stride(d);
        }
    }
    __syncthreads();
    // counting sort + arithmetic segment base (no scan)
    for (int v = tid; v < K_; v += 256) {
        int d    = s_deg[v];
        int slot = atomicAdd(&s_hist[d & 31], 1);
        int base = s_binBase[d] + (slot - s_binStart[d]) * seg_stride(d);
        s_perm[slot]  = v | (d << 16);
        s_offslot[v]  = base | (slot << 16);
    }
    __syncthreads();
    // slot-owner registers (pv, od, lr) + per-check t5
    int      pv[5];                      // slot -> VN id
    unsigned od[5];                      // base | deg<<16
    float    lr[5];                      // channel LLR of owned VN
    #pragma unroll
    for (int k = 0; k < 5; ++k) {
        int s = tid + 256 * k;
        if (s < K_) {
            int w = s_perm[s];
            int v = w & 0xFFFF;
            int d = w >> 16;
            int base = s_binBase[d] + (s - s_binStart[d]) * seg_stride(d);
            pv[k] = v;
            od[k] = (unsigned)base | ((unsigned)d << 16);
            lr[k] = s_tot[v];
        } else { pv[k] = 0; od[k] = 0; lr[k] = 0.0f; }
    }
    float t5[5];
    unsigned vnp[5][5];                  // slot | pos<<16
    float    c2vr[5][5];                 // previous c2v (registers)
    #pragma unroll
    for (int kk = 0; kk < 5; ++kk) {
        int m = tid + 256 * kk;
        if (m < M_) {
            #pragma unroll
            for (int j = 0; j < 5; ++j) {
                int v = ev[kk][j];
                int r = atomicAdd(&s_cnt[v], 1);
                int w = s_offslot[v];
                unsigned pos  = (unsigned)((w & 0xFFFF) + r);
                unsigned slot = (unsigned)(w >> 16);
                vnp[kk][j]  = slot | (pos << 16);
                c2vr[kk][j] = 0.0f;
            }
            float lrP = s_tot[K_ + m];
            float av  = fminf(fmaxf(fabsf(lrP), 1e-6f), 20.0f);
            float e   = __expf(-av);
            float tm  = __fdividef(1.0f - e, 1.0f + e);
            t5[kk] = copysignf(tm, lrP);
        } else { t5[kk] = 0.0f; }
    }
    __syncthreads();
    // scratch fully consumed -> become the message array
    for (int i = tid; i < CAP_; i += 256) s_c2v[i] = 0.0f;
    __syncthreads();
    // ======================================================================

    // ---- sum-product BP, flooding ----
    for (int it = 0; it < NITER_; ++it) {
        // Phase A: marginals, slot-indexed (stride-1 writes; odd-stride
        // segment reads -> both conflict-free)
        #pragma unroll
        for (int k = 0; k < 5; ++k) {
            int s = tid + 256 * k;
            if (s < K_) {
                int base = (int)(od[k] & 0xFFFFu);
                int dg   = (int)(od[k] >> 16);
                float mg = lr[k];
                for (int d = 0; d < dg; ++d) mg += s_c2v[base + d];
                s_tot[s] = mg;
            }
        }
        __syncthreads();
        // Phase B: CN update, prefix/suffix products; old c2v from registers
        #pragma unroll
        for (int kk = 0; kk < 5; ++kk) {
            int m = tid + 256 * kk;
            if (m < M_) {
                float tj[5];
                #pragma unroll
                for (int j = 0; j < 5; ++j) {
                    unsigned w = vnp[kk][j];
                    float v2c = s_tot[w & 0xFFFFu] - c2vr[kk][j];
                    float av  = fminf(fmaxf(fabsf(v2c), 1e-6f), 20.0f);
                    float e   = __expf(-av);
                    float tm  = __fdividef(1.0f - e, 1.0f + e);
                    tj[j] = copysignf(tm, v2c);
                }
                float qv[5];
                float pr = t5[kk];
                #pragma unroll
                for (int j = 0; j < 5; ++j) { qv[j] = pr; pr *= tj[j]; }
                float sf = 1.0f;
                #pragma unroll
                for (int j = 4; j >= 0; --j) { qv[j] *= sf; sf *= tj[j]; }
                #pragma unroll
                for (int j = 0; j < 5; ++j) {
                    float q = fminf(fmaxf(qv[j], -0.99999988f), 0.99999988f);
                    float r = __logf(__fdividef(1.0f + q, 1.0f - q));
                    s_c2v[vnp[kk][j] >> 16] = r;
                    c2vr[kk][j] = r;
                }
            }
        }
        __syncthreads();
    }

    // ---- final marginal + hard decision on info VNs ----
    #pragma unroll
    for (int k = 0; k < 5; ++k) {
        int s = tid + 256 * k;
        if (s < K_) {
            int base = (int)(od[k] & 0xFFFFu);
            int dg   = (int)(od[k] >> 16);
            float mg = lr[k];
            for (int d = 0; d < dg; ++d) mg += s_c2v[base + d];
            out[(size_t)BATCH_ * K_ + b * K_ + pv[k]] = (mg < 0.0f) ? 1.0f : 0.0f;
        }
    }
}

extern "C" void kernel_launch(void* const* d_in, const int* in_sizes, int n_in,
                              void* d_out, int out_size, void* d_ws, size_t ws_size,
                              hipStream_t stream) {
    const int*   bits    = (const int*)  d_in[0];
    const int*   a_idx   = (const int*)  d_in[1];
    // d_in[2] = edge_cn (implicit: contiguous groups of 6) — unused
    const int*   edge_vn = (const int*)  d_in[3];
    const float* pre     = (const float*)d_in[4];
    const float* pim     = (const float*)d_in[5];
    const float* nre     = (const float*)d_in[6];
    const float* nim     = (const float*)d_in[7];
    const float* ebno    = (const float*)d_in[8];

    link_kernel<<<BATCH_, 256, 0, stream>>>(bits, a_idx, pre, pim, nre, nim,
                                            ebno, edge_vn, (float*)d_out);
}